// Round 1
// baseline (1634.777 us; speedup 1.0000x reference)
//
#include <hip/hip_runtime.h>

#define N_NODES 100000
#define N_EDGES 800000
#define FEAT    128

// ---------------- CSR build ----------------

__global__ void k_hist(const int* __restrict__ eidx, int* __restrict__ counts) {
  int i = blockIdx.x * blockDim.x + threadIdx.x;
  if (i >= 2 * N_EDGES) return;
  // out_idx = concat([receivers, senders]); receivers = eidx[E..2E), senders = eidx[0..E)
  int node = (i < N_EDGES) ? eidx[N_EDGES + i] : eidx[i - N_EDGES];
  atomicAdd(&counts[node], 1);
}

__global__ __launch_bounds__(1024) void k_scan(const int* __restrict__ counts,
                                               int* __restrict__ offsets,
                                               int* __restrict__ cursor) {
  __shared__ int sums[1024];
  int tid = threadIdx.x;
  const int chunk = (N_NODES + 1023) / 1024;  // 98
  int beg = tid * chunk;
  int end = min(beg + chunk, N_NODES);
  if (beg > N_NODES) beg = N_NODES;
  int s = 0;
  for (int i = beg; i < end; i++) s += counts[i];
  sums[tid] = s;
  __syncthreads();
  // Hillis-Steele inclusive scan over 1024 partials
  for (int ofs = 1; ofs < 1024; ofs <<= 1) {
    int v = 0;
    if (tid >= ofs) v = sums[tid - ofs];
    __syncthreads();
    sums[tid] += v;
    __syncthreads();
  }
  int run = sums[tid] - s;  // exclusive prefix of this thread's chunk
  for (int i = beg; i < end; i++) {
    offsets[i] = run;
    cursor[i] = run;
    run += counts[i];
  }
}

__global__ void k_fill(const int* __restrict__ eidx, int* __restrict__ cursor,
                       int* __restrict__ rowlist) {
  int i = blockIdx.x * blockDim.x + threadIdx.x;
  if (i >= 2 * N_EDGES) return;
  int node = (i < N_EDGES) ? eidx[N_EDGES + i] : eidx[i - N_EDGES];
  int pos = atomicAdd(&cursor[node], 1);
  rowlist[pos] = i;
}

// ---------------- fused attention + aggregation ----------------
// One wave per node. Lane owns features {2*lane, 2*lane+1}.
// agg[n] = (sum_e exp(logit_e) * row_e) / (sum_e exp(logit_e))  -- softmax w/o
// max-subtraction (logits ~N(0,1), safe in fp32), normalization deferred so
// each edge row is read exactly once.
__global__ __launch_bounds__(64) void k_attn(const float* __restrict__ node_attr,
                                             const float* __restrict__ edge_attr,
                                             const int* __restrict__ offsets,
                                             const int* __restrict__ counts,
                                             const int* __restrict__ rowlist,
                                             float* __restrict__ agg) {
  int n = blockIdx.x;
  int lane = threadIdx.x;
  float2 x = *(const float2*)&node_attr[(size_t)n * FEAT + lane * 2];
  int beg = offsets[n];
  int deg = counts[n];
  float accx = 0.f, accy = 0.f, den = 0.f;
  const float inv_sqrtF = 0.08838834764831845f;  // 1/sqrt(128)
  for (int t = 0; t < deg; t++) {
    int r = rowlist[beg + t];
    const float* src = (r < N_EDGES)
        ? (edge_attr + (size_t)r * (2 * FEAT))
        : (edge_attr + (size_t)(r - N_EDGES) * (2 * FEAT) + FEAT);
    float2 v = *(const float2*)&src[lane * 2];
    float p = v.x * x.x + v.y * x.y;
#pragma unroll
    for (int m = 1; m < 64; m <<= 1) p += __shfl_xor(p, m, 64);
    float e = __expf(p * inv_sqrtF);
    den += e;
    accx += e * v.x;
    accy += e * v.y;
  }
  float inv = (den > 0.f) ? 1.f / den : 0.f;
  float2 o;
  o.x = accx * inv;
  o.y = accy * inv;
  *(float2*)&agg[(size_t)n * FEAT + lane * 2] = o;
}

// ---------------- linear layer: out = [agg | node_attr] @ W + b ----------------
// fp32 tiled GEMM: BM=128 nodes, BN=128 outs, BK=32, 256 threads, 8x8 accs.
#define BM 128
#define BN 128
#define BK 32

__global__ __launch_bounds__(256) void k_gemm(const float* __restrict__ agg,
                                              const float* __restrict__ node_attr,
                                              const float* __restrict__ W,
                                              const float* __restrict__ bias,
                                              float* __restrict__ out) {
  __shared__ float As[BK][BM + 4];  // transposed: As[k][m]
  __shared__ float Bs[BK][BN + 4];
  int tid = threadIdx.x;
  int tx = tid & 15;
  int ty = tid >> 4;
  int row0 = blockIdx.x * BM;
  float acc[8][8];
#pragma unroll
  for (int i = 0; i < 8; i++)
#pragma unroll
    for (int j = 0; j < 8; j++) acc[i][j] = 0.f;

  for (int kc = 0; kc < 2 * FEAT; kc += BK) {
    const float* A = (kc < FEAT) ? agg : node_attr;
    int ak = (kc < FEAT) ? kc : kc - FEAT;
    // stage A tile (transposed into LDS)
    {
      int r = tid >> 3;               // 0..31
      int kcol = (tid & 7) * 4;       // 0,4,..,28
#pragma unroll
      for (int i = 0; i < 4; i++) {
        int rr = r + 32 * i;
        int gr = row0 + rr;
        float4 v = make_float4(0.f, 0.f, 0.f, 0.f);
        if (gr < N_NODES) v = *(const float4*)&A[(size_t)gr * FEAT + ak + kcol];
        As[kcol + 0][rr] = v.x;
        As[kcol + 1][rr] = v.y;
        As[kcol + 2][rr] = v.z;
        As[kcol + 3][rr] = v.w;
      }
    }
    // stage W tile
    {
      int krow = tid >> 5;            // 0..7
      int ncol = (tid & 31) * 4;      // 0..124
#pragma unroll
      for (int i = 0; i < 4; i++) {
        int kk = krow + 8 * i;
        float4 v = *(const float4*)&W[(size_t)(kc + kk) * FEAT + ncol];
        *(float4*)&Bs[kk][ncol] = v;
      }
    }
    __syncthreads();
#pragma unroll
    for (int k = 0; k < BK; k++) {
      float4 a0 = *(const float4*)&As[k][ty * 4];
      float4 a1 = *(const float4*)&As[k][64 + ty * 4];
      float4 b0 = *(const float4*)&Bs[k][tx * 4];
      float4 b1 = *(const float4*)&Bs[k][64 + tx * 4];
      float a[8] = {a0.x, a0.y, a0.z, a0.w, a1.x, a1.y, a1.z, a1.w};
      float bb[8] = {b0.x, b0.y, b0.z, b0.w, b1.x, b1.y, b1.z, b1.w};
#pragma unroll
      for (int i = 0; i < 8; i++)
#pragma unroll
        for (int j = 0; j < 8; j++) acc[i][j] += a[i] * bb[j];
    }
    __syncthreads();
  }

  float4 bv0 = *(const float4*)&bias[tx * 4];
  float4 bv1 = *(const float4*)&bias[64 + tx * 4];
  float bb[8] = {bv0.x, bv0.y, bv0.z, bv0.w, bv1.x, bv1.y, bv1.z, bv1.w};
#pragma unroll
  for (int i = 0; i < 8; i++) {
    int rr = (i < 4) ? (ty * 4 + i) : (64 + ty * 4 + (i - 4));
    int gr = row0 + rr;
    if (gr >= N_NODES) continue;
    float4 o0, o1;
    o0.x = acc[i][0] + bb[0];
    o0.y = acc[i][1] + bb[1];
    o0.z = acc[i][2] + bb[2];
    o0.w = acc[i][3] + bb[3];
    o1.x = acc[i][4] + bb[4];
    o1.y = acc[i][5] + bb[5];
    o1.z = acc[i][6] + bb[6];
    o1.w = acc[i][7] + bb[7];
    *(float4*)&out[(size_t)gr * FEAT + tx * 4] = o0;
    *(float4*)&out[(size_t)gr * FEAT + 64 + tx * 4] = o1;
  }
}

// ---------------- launch ----------------

extern "C" void kernel_launch(void* const* d_in, const int* in_sizes, int n_in,
                              void* d_out, int out_size, void* d_ws, size_t ws_size,
                              hipStream_t stream) {
  const float* node_attr = (const float*)d_in[0];
  const float* edge_attr = (const float*)d_in[1];
  const int* eidx = (const int*)d_in[2];
  const float* W = (const float*)d_in[3];
  const float* bias = (const float*)d_in[4];
  float* out = (float*)d_out;

  // workspace layout (bytes): counts[0, 400000) offsets[400000, 800000)
  // cursor[800000, 1200000) rowlist[1200000, 7600000) agg[7600000, 58800000)
  char* ws = (char*)d_ws;
  int* counts = (int*)(ws);
  int* offsets = (int*)(ws + 400000);
  int* cursor = (int*)(ws + 800000);
  int* rowlist = (int*)(ws + 1200000);
  float* agg = (float*)(ws + 7600000);

  hipMemsetAsync(counts, 0, N_NODES * sizeof(int), stream);
  int nb = (2 * N_EDGES + 255) / 256;
  k_hist<<<nb, 256, 0, stream>>>(eidx, counts);
  k_scan<<<1, 1024, 0, stream>>>(counts, offsets, cursor);
  k_fill<<<nb, 256, 0, stream>>>(eidx, cursor, rowlist);
  k_attn<<<N_NODES, 64, 0, stream>>>(node_attr, edge_attr, offsets, counts, rowlist, agg);
  k_gemm<<<(N_NODES + BM - 1) / BM, 256, 0, stream>>>(agg, node_attr, W, bias, out);
}